// Round 9
// baseline (863.694 us; speedup 1.0000x reference)
//
#include <hip/hip_runtime.h>

// Node model GNN — bucket-resident fused aggregation:
//   edge MLP: h = relu(relu([x[src],ea]@W1+b1)@W2+b2)   (W3 commuted past the mean)
//   node: out = relu(mean@(W3@W4mid) + x-terms + (b4+b3@W4mid))@W5+b5   (W3 folded)
// Pipeline: bhist -> bscan -> binA (bucket-sort full payload, merged writes)
//           -> bucket_kernel (MFMA MLP + LDS ds_add aggregation + mean, per 256-node bucket)
//           -> node MLP.  No dst-exact sort, no global atomics, no agg memset.
constexpr int HID = 64;
constexpr int BN_SHIFT = 8;            // 256 nodes per bucket
constexpr int BROWS = 1 << BN_SHIFT;
constexpr int CH = 8192;               // edges per histogram/binA workgroup

typedef __attribute__((ext_vector_type(8))) short s8v;    // 8 bf16 MFMA A/B frag
typedef __attribute__((ext_vector_type(4))) float f32x4;  // MFMA C/D frag
typedef __attribute__((ext_vector_type(4))) unsigned int u32x4;

__device__ __forceinline__ s8v as_s8(u32x4 v) { s8v r; __builtin_memcpy(&r, &v, 16); return r; }

// ---------- pass 0a: split W2 into transposed bf16 hi/lo tables ----------
__global__ __launch_bounds__(64) void pack_w2_kernel(
    const float* __restrict__ W2, unsigned short* __restrict__ Bhi,
    unsigned short* __restrict__ Blo)
{
    const int f = blockIdx.x;    // 64 blocks
    const int k = threadIdx.x;   // 64 threads
    const float w = W2[k * 64 + f];
    const unsigned int u = __float_as_uint(w);
    const float hf = __uint_as_float(u & 0xffff0000u);
    const float r = w - hf;
    Bhi[f * 64 + k] = (unsigned short)(u >> 16);
    Blo[f * 64 + k] = (unsigned short)(__float_as_uint(r) >> 16);
}

// ---------- pass 0b: fold W3 into W4's middle rows ----------
__global__ __launch_bounds__(128) void pack_w34_kernel(
    const float* __restrict__ W3, const float* __restrict__ b3,
    const float* __restrict__ W4, const float* __restrict__ b4,
    float* __restrict__ C, float* __restrict__ b4p)
{
    const int t = blockIdx.x;    // 0..64; t==64 computes the folded bias
    const int j = threadIdx.x;
    if (j >= 67) return;
    if (t < 64) {
        float s = 0.f;
        for (int k = 0; k < 64; ++k) s = fmaf(W3[t * 64 + k], W4[(2 + k) * 67 + j], s);
        C[t * 67 + j] = s;
    } else {
        float s = b4[j];
        for (int k = 0; k < 64; ++k) s = fmaf(b3[k], W4[(2 + k) * 67 + j], s);
        b4p[j] = s;
    }
}

// ---------- pass 1: bucket histogram (LDS-aggregated) ----------
__global__ __launch_bounds__(256) void bhist_kernel(
    const int* __restrict__ ei, int* __restrict__ bhist, int E)
{
    __shared__ int h[512];
    const int tid = threadIdx.x;
    for (int i = tid; i < 512; i += 256) h[i] = 0;
    __syncthreads();
    const int e0 = blockIdx.x * CH;
    #pragma unroll
    for (int r = 0; r < CH / 256; ++r) {
        const int e = e0 + r * 256 + tid;
        if (e < E) atomicAdd(&h[ei[E + e] >> BN_SHIFT], 1);
    }
    __syncthreads();
    for (int i = tid; i < 512; i += 256)
        if (h[i]) atomicAdd(&bhist[i], h[i]);
}

// ---------- pass 2: bucket offsets scan (single block) ----------
__global__ __launch_bounds__(512) void bscan_kernel(
    const int* __restrict__ bhist, int* __restrict__ boff,
    int* __restrict__ bcur, int NB)
{
    __shared__ int sm[512];
    const int t = threadIdx.x;
    const int v = (t < NB) ? bhist[t] : 0;
    sm[t] = v;
    __syncthreads();
    for (int off = 1; off < 512; off <<= 1) {
        int x = (t >= off) ? sm[t - off] : 0;
        __syncthreads();
        sm[t] += x;
        __syncthreads();
    }
    const int excl = sm[t] - v;
    if (t < NB) { boff[t] = excl; bcur[t] = excl; }
    if (t == NB - 1) boff[NB] = excl + v;
}

// ---------- pass 3: bucket-sort full payload (merged writes) ----------
__global__ __launch_bounds__(256) void binA_kernel(
    const int* __restrict__ ei, const float* __restrict__ x,
    const float* __restrict__ ea, int* __restrict__ bcur,
    float4* __restrict__ A, int E, int NB)
{
    __shared__ int hist[512];
    __shared__ int base_s[512];
    const int tid = threadIdx.x;
    const int e0 = blockIdx.x * CH;

    for (int i = tid; i < 512; i += 256) hist[i] = 0;
    __syncthreads();
    #pragma unroll
    for (int r = 0; r < CH / 256; ++r) {
        const int e = e0 + r * 256 + tid;
        if (e < E) atomicAdd(&hist[ei[E + e] >> BN_SHIFT], 1);
    }
    __syncthreads();
    for (int i = tid; i < 512; i += 256) {
        const int h = hist[i];
        base_s[i] = h ? atomicAdd(&bcur[i], h) : 0;   // one reservation per (block,bucket)
        hist[i] = 0;                                   // reuse as local rank cursor
    }
    __syncthreads();
    #pragma unroll
    for (int r = 0; r < CH / 256; ++r) {
        const int e = e0 + r * 256 + tid;
        if (e < E) {
            const int d = ei[E + e];                   // L2-hot (2nd read of chunk)
            const int src = ei[e];                     // sequential stream
            const float w = ea[e];                     // sequential stream
            const float2 xv = ((const float2*)x)[src]; // gather into 800KB (L2-fit)
            const int b = d >> BN_SHIFT;
            const int pos = base_s[b] + atomicAdd(&hist[b], 1);
            A[pos] = make_float4(xv.x, xv.y, w, __int_as_float(d));
        }
    }
}

// ---------- pass 4: bucket-resident MFMA edge MLP + LDS aggregation + mean ----------
// One 512-thread WG per 256-node bucket. aggl[256][65] (stride 65: dst-randomized
// banks; col 64 = edge count). Lane (am,aq) computes its own A-fragment in registers
// (feats aq*8..+7 of edge eb*16+am) -> no h1 LDS staging. acc kept to 2 eb at a
// time (32 regs) -> VGPR<=128 -> 2 WGs/CU.
__global__ __launch_bounds__(512, 4) void bucket_kernel(
    const float4* __restrict__ A, const int* __restrict__ boff,
    const float* __restrict__ W1, const float* __restrict__ b1,
    const unsigned short* __restrict__ Bhi, const unsigned short* __restrict__ Blo,
    const float* __restrict__ b2,
    float* __restrict__ agg, int N)
{
    __shared__ float aggl[BROWS * 65];        // 66,560 B
    __shared__ float4 gst[512];               // 8 KB: per-wave 64 edge records
    const int b = blockIdx.x;
    const int lo = b << BN_SHIFT;
    const int span = min(BROWS, N - lo);
    const int start = boff[b], end = boff[b + 1];
    const int tid = threadIdx.x;

    for (int i = tid; i < BROWS * 65; i += 512) aggl[i] = 0.f;
    __syncthreads();

    const int wv = tid >> 6, lane = tid & 63;
    const int am = lane & 15, aq = lane >> 4;
    float4* gw = &gst[wv * 64];

    float bias[4];
    #pragma unroll
    for (int fb = 0; fb < 4; ++fb) bias[fb] = b2[fb * 16 + am];

    const int nIter = (end - start + 511) >> 9;
    for (int it = 0; it < nIter; ++it) {
        const int i = start + (it << 9) + (wv << 6) + lane;
        float4 g = make_float4(0.f, 0.f, 0.f, 0.f);
        int dstl = -1;
        if (i < end) { g = A[i]; dstl = __float_as_int(g.w) - lo; }
        gw[lane] = g;                                        // in-order per-wave LDS
        if (dstl >= 0) atomicAdd(&aggl[dstl * 65 + 64], 1.0f);  // count

        #pragma unroll
        for (int half = 0; half < 2; ++half) {
            f32x4 acc[2][4];
            #pragma unroll
            for (int e2 = 0; e2 < 2; ++e2)
                #pragma unroll
                for (int fb = 0; fb < 4; ++fb) acc[e2][fb] = (f32x4){0.f, 0.f, 0.f, 0.f};

            #pragma unroll
            for (int kb = 0; kb < 2; ++kb) {
                // W1 fragment cache: this lane's 8 feats (j0..j0+7), 4 rows
                const int j0 = kb * 32 + aq * 8;
                float w1x[8], w1y[8], w1z[8], w1b[8];
                *(float4*)&w1x[0] = *(const float4*)(W1 + j0);
                *(float4*)&w1x[4] = *(const float4*)(W1 + j0 + 4);
                *(float4*)&w1y[0] = *(const float4*)(W1 + 64 + j0);
                *(float4*)&w1y[4] = *(const float4*)(W1 + 64 + j0 + 4);
                *(float4*)&w1z[0] = *(const float4*)(W1 + 128 + j0);
                *(float4*)&w1z[4] = *(const float4*)(W1 + 128 + j0 + 4);
                *(float4*)&w1b[0] = *(const float4*)(b1 + j0);
                *(float4*)&w1b[4] = *(const float4*)(b1 + j0 + 4);

                s8v ah[2], al[2];
                #pragma unroll
                for (int e2 = 0; e2 < 2; ++e2) {
                    const int eb = half * 2 + e2;
                    const float4 ge = gw[eb * 16 + am];      // broadcast-ish read
                    unsigned int hp[4], lp[4];
                    #pragma unroll
                    for (int jp = 0; jp < 4; ++jp) {
                        float v0 = fmaf(ge.x, w1x[2*jp],   fmaf(ge.y, w1y[2*jp],   fmaf(ge.z, w1z[2*jp],   w1b[2*jp])));
                        float v1 = fmaf(ge.x, w1x[2*jp+1], fmaf(ge.y, w1y[2*jp+1], fmaf(ge.z, w1z[2*jp+1], w1b[2*jp+1])));
                        v0 = fmaxf(v0, 0.f); v1 = fmaxf(v1, 0.f);
                        const unsigned int u0 = __float_as_uint(v0), u1 = __float_as_uint(v1);
                        hp[jp] = (u0 >> 16) | (u1 & 0xffff0000u);
                        const float r0 = v0 - __uint_as_float(u0 & 0xffff0000u);
                        const float r1 = v1 - __uint_as_float(u1 & 0xffff0000u);
                        lp[jp] = (__float_as_uint(r0) >> 16) | (__float_as_uint(r1) & 0xffff0000u);
                    }
                    ah[e2] = as_s8((u32x4){hp[0], hp[1], hp[2], hp[3]});
                    al[e2] = as_s8((u32x4){lp[0], lp[1], lp[2], lp[3]});
                }
                #pragma unroll
                for (int fb = 0; fb < 4; ++fb) {
                    const int bo = (fb * 16 + am) * 64 + kb * 32 + aq * 8;
                    const s8v bh = *(const s8v*)(Bhi + bo);
                    const s8v bl = *(const s8v*)(Blo + bo);
                    #pragma unroll
                    for (int e2 = 0; e2 < 2; ++e2) {
                        acc[e2][fb] = __builtin_amdgcn_mfma_f32_16x16x32_bf16(ah[e2], bh, acc[e2][fb], 0, 0, 0);
                        acc[e2][fb] = __builtin_amdgcn_mfma_f32_16x16x32_bf16(ah[e2], bl, acc[e2][fb], 0, 0, 0);
                        acc[e2][fb] = __builtin_amdgcn_mfma_f32_16x16x32_bf16(al[e2], bh, acc[e2][fb], 0, 0, 0);
                    }
                }
            }

            // epilogue: bias+relu, ds_add into aggl rows (dst-randomized banks)
            #pragma unroll
            for (int e2 = 0; e2 < 2; ++e2) {
                const int eb = half * 2 + e2;
                int drow[4];
                #pragma unroll
                for (int r = 0; r < 4; ++r)
                    drow[r] = __shfl(dstl, eb * 16 + aq * 4 + r);
                #pragma unroll
                for (int fb = 0; fb < 4; ++fb) {
                    const int feat = fb * 16 + am;
                    #pragma unroll
                    for (int r = 0; r < 4; ++r) {
                        if (drow[r] >= 0) {
                            const float v = fmaxf(acc[e2][fb][r] + bias[fb], 0.f);
                            atomicAdd(&aggl[drow[r] * 65 + feat], v);
                        }
                    }
                }
            }
        }
    }
    __syncthreads();

    // flush means: 2 threads per row, 32 feats each
    const int row = tid >> 1;
    const int f0 = (tid & 1) << 5;
    if (row < span) {
        const float c = aggl[row * 65 + 64];
        const float inv = 1.f / fmaxf(c, 1.f);
        float4* op = (float4*)(agg + (size_t)(lo + row) * HID + f0);
        #pragma unroll
        for (int q = 0; q < 8; ++q) {
            float4 vv;
            vv.x = aggl[row * 65 + f0 + q * 4 + 0] * inv;
            vv.y = aggl[row * 65 + f0 + q * 4 + 1] * inv;
            vv.z = aggl[row * 65 + f0 + q * 4 + 2] * inv;
            vv.w = aggl[row * 65 + f0 + q * 4 + 3] * inv;
            op[q] = vv;
        }
    }
}

// ---------- pass 5: node MLP (W3 pre-folded into C; agg already holds means) ----------
__global__ __launch_bounds__(256) void node_kernel(
    const float* __restrict__ x, const float* __restrict__ u,
    const int* __restrict__ batch,
    const float* __restrict__ W4, const float* __restrict__ W5,
    const float* __restrict__ b5,
    const float* __restrict__ C, const float* __restrict__ b4p,
    const float* __restrict__ agg,
    float* __restrict__ out, int N)
{
    const int n = blockIdx.x * 256 + threadIdx.x;
    if (n >= N) return;

    const float4* ar = (const float4*)(agg + (size_t)n * HID);

    float acc[67];
    #pragma unroll
    for (int j = 0; j < 67; ++j) acc[j] = b4p[j];

    #pragma unroll 4
    for (int q = 0; q < 16; ++q) {
        const float4 m4 = ar[q];
        const float mk[4] = {m4.x, m4.y, m4.z, m4.w};
        #pragma unroll
        for (int r = 0; r < 4; ++r) {
            const float* cr = C + (q * 4 + r) * 67;
            #pragma unroll
            for (int j = 0; j < 67; ++j) acc[j] = fmaf(mk[r], cr[j], acc[j]);
        }
    }

    const float2 xv = ((const float2*)x)[n];
    const float ub = u[batch[n]];
    #pragma unroll
    for (int j = 0; j < 67; ++j) acc[j] = fmaf(xv.x, W4[j], acc[j]);
    #pragma unroll
    for (int j = 0; j < 67; ++j) acc[j] = fmaf(xv.y, W4[67 + j], acc[j]);
    #pragma unroll
    for (int j = 0; j < 67; ++j) acc[j] = fmaf(ub, W4[66 * 67 + j], acc[j]);

    float o0 = b5[0], o1 = b5[1];
    #pragma unroll
    for (int j = 0; j < 67; ++j) {
        const float z = fmaxf(acc[j], 0.f);
        o0 = fmaf(z, W5[2 * j], o0);
        o1 = fmaf(z, W5[2 * j + 1], o1);
    }
    out[2 * n] = o0;
    out[2 * n + 1] = o1;
}

extern "C" void kernel_launch(void* const* d_in, const int* in_sizes, int n_in,
                              void* d_out, int out_size, void* d_ws, size_t ws_size,
                              hipStream_t stream) {
    const float* x     = (const float*)d_in[0];
    const int*   ei    = (const int*)  d_in[1];
    const float* ea    = (const float*)d_in[2];
    const float* u     = (const float*)d_in[3];
    const int*   batch = (const int*)  d_in[4];
    const float* W1 = (const float*)d_in[5];  const float* b1 = (const float*)d_in[6];
    const float* W2 = (const float*)d_in[7];  const float* b2 = (const float*)d_in[8];
    const float* W3 = (const float*)d_in[9];  const float* b3 = (const float*)d_in[10];
    const float* W4 = (const float*)d_in[11]; const float* b4 = (const float*)d_in[12];
    const float* W5 = (const float*)d_in[13]; const float* b5 = (const float*)d_in[14];

    const int N = in_sizes[0] / 2;   // 100000
    const int E = in_sizes[2];       // 1600000
    const int NB = (N + BROWS - 1) >> BN_SHIFT;   // 391 buckets

    // workspace layout (~51.3 MB)
    char* w = (char*)d_ws;
    size_t o = 0;
    int* bhist = (int*)(w + o); o += 512 * 4;
    int* boff  = (int*)(w + o); o += 513 * 4;
    int* bcur  = (int*)(w + o); o += 512 * 4;
    o = (o + 15) & ~(size_t)15;
    unsigned short* Bhi = (unsigned short*)(w + o); o += 64 * 64 * 2;
    unsigned short* Blo = (unsigned short*)(w + o); o += 64 * 64 * 2;
    float* Cmat = (float*)(w + o); o += 64 * 67 * 4;
    float* b4p  = (float*)(w + o); o += 68 * 4;
    o = (o + 15) & ~(size_t)15;
    float4* Abuf = (float4*)(w + o); o += (size_t)E * 16;     // bucket-sorted payload
    float*  agg  = (float*)(w + o);  o += (size_t)N * HID * 4; // per-node means

    const int nCH = (E + CH - 1) / CH;   // 196

    hipMemsetAsync(bhist, 0, 512 * 4, stream);
    pack_w2_kernel<<<64, 64, 0, stream>>>(W2, Bhi, Blo);
    pack_w34_kernel<<<65, 128, 0, stream>>>(W3, b3, W4, b4, Cmat, b4p);
    bhist_kernel<<<nCH, 256, 0, stream>>>(ei, bhist, E);
    bscan_kernel<<<1, 512, 0, stream>>>(bhist, boff, bcur, NB);
    binA_kernel<<<nCH, 256, 0, stream>>>(ei, x, ea, bcur, Abuf, E, NB);
    bucket_kernel<<<NB, 512, 0, stream>>>(Abuf, boff, W1, b1, Bhi, Blo, b2, agg, N);
    node_kernel<<<(N + 255) / 256, 256, 0, stream>>>(x, u, batch, W4, W5, b5, Cmat, b4p,
                                                     agg, (float*)d_out, N);
}

// Round 10
// 810.030 us; speedup vs baseline: 1.0662x; 1.0662x over previous
//
#include <hip/hip_runtime.h>

// Node model GNN — bucket-resident fused aggregation, take 2 (spill-free):
//   edge MLP: h = relu(relu([x[src],ea]@W1+b1)@W2+b2)   (W3 commuted past the mean)
//   node: out = relu(mean@(W3@W4mid) + x-terms + (b4+b3@W4mid))@W5+b5   (W3 folded)
// Pipeline: bhist -> bscan -> binA (bucket-sort full payload, merged writes)
//           -> bucket_kernel (round-8 proven MFMA core + LDS ds_add aggregation + mean)
//           -> node MLP.  No dst-exact sort, no global atomics, no agg memset.
constexpr int HID = 64;
constexpr int BN_SHIFT = 7;            // 128 nodes per bucket
constexpr int BROWS = 1 << BN_SHIFT;
constexpr int CH = 8192;               // edges per histogram/binA workgroup
constexpr int NBMAX = 1024;

typedef __attribute__((ext_vector_type(8))) short s8v;    // 8 bf16 MFMA A/B frag
typedef __attribute__((ext_vector_type(4))) float f32x4;  // MFMA C/D frag
typedef unsigned long long ull;

// ---------- pass 0a: split W2 into transposed bf16 hi/lo tables ----------
__global__ __launch_bounds__(64) void pack_w2_kernel(
    const float* __restrict__ W2, unsigned short* __restrict__ Bhi,
    unsigned short* __restrict__ Blo)
{
    const int f = blockIdx.x;    // 64 blocks
    const int k = threadIdx.x;   // 64 threads
    const float w = W2[k * 64 + f];
    const unsigned int u = __float_as_uint(w);
    const float hf = __uint_as_float(u & 0xffff0000u);
    const float r = w - hf;
    Bhi[f * 64 + k] = (unsigned short)(u >> 16);
    Blo[f * 64 + k] = (unsigned short)(__float_as_uint(r) >> 16);
}

// ---------- pass 0b: fold W3 into W4's middle rows ----------
__global__ __launch_bounds__(128) void pack_w34_kernel(
    const float* __restrict__ W3, const float* __restrict__ b3,
    const float* __restrict__ W4, const float* __restrict__ b4,
    float* __restrict__ C, float* __restrict__ b4p)
{
    const int t = blockIdx.x;    // 0..64; t==64 computes the folded bias
    const int j = threadIdx.x;
    if (j >= 67) return;
    if (t < 64) {
        float s = 0.f;
        for (int k = 0; k < 64; ++k) s = fmaf(W3[t * 64 + k], W4[(2 + k) * 67 + j], s);
        C[t * 67 + j] = s;
    } else {
        float s = b4[j];
        for (int k = 0; k < 64; ++k) s = fmaf(b3[k], W4[(2 + k) * 67 + j], s);
        b4p[j] = s;
    }
}

// ---------- pass 1: bucket histogram (LDS-aggregated) ----------
__global__ __launch_bounds__(256) void bhist_kernel(
    const int* __restrict__ ei, int* __restrict__ bhist, int E, int NB)
{
    __shared__ int h[NBMAX];
    const int tid = threadIdx.x;
    for (int i = tid; i < NB; i += 256) h[i] = 0;
    __syncthreads();
    const int e0 = blockIdx.x * CH;
    #pragma unroll
    for (int r = 0; r < CH / 256; ++r) {
        const int e = e0 + r * 256 + tid;
        if (e < E) atomicAdd(&h[ei[E + e] >> BN_SHIFT], 1);
    }
    __syncthreads();
    for (int i = tid; i < NB; i += 256)
        if (h[i]) atomicAdd(&bhist[i], h[i]);
}

// ---------- pass 2: bucket offsets scan (single 1024-thread block) ----------
__global__ __launch_bounds__(1024) void bscan_kernel(
    const int* __restrict__ bhist, int* __restrict__ boff,
    int* __restrict__ bcur, int NB)
{
    __shared__ int sm[1024];
    const int t = threadIdx.x;
    const int v = (t < NB) ? bhist[t] : 0;
    sm[t] = v;
    __syncthreads();
    for (int off = 1; off < 1024; off <<= 1) {
        int x = (t >= off) ? sm[t - off] : 0;
        __syncthreads();
        sm[t] += x;
        __syncthreads();
    }
    const int excl = sm[t] - v;
    if (t < NB) { boff[t] = excl; bcur[t] = excl; }
    if (t == NB - 1) boff[NB] = excl + v;
}

// ---------- pass 3: bucket-sort full payload (merged writes) ----------
__global__ __launch_bounds__(256) void binA_kernel(
    const int* __restrict__ ei, const float* __restrict__ x,
    const float* __restrict__ ea, int* __restrict__ bcur,
    float4* __restrict__ A, int E, int NB)
{
    __shared__ int hist[NBMAX];
    __shared__ int base_s[NBMAX];
    const int tid = threadIdx.x;
    const int e0 = blockIdx.x * CH;

    for (int i = tid; i < NB; i += 256) hist[i] = 0;
    __syncthreads();
    #pragma unroll
    for (int r = 0; r < CH / 256; ++r) {
        const int e = e0 + r * 256 + tid;
        if (e < E) atomicAdd(&hist[ei[E + e] >> BN_SHIFT], 1);
    }
    __syncthreads();
    for (int i = tid; i < NB; i += 256) {
        const int h = hist[i];
        base_s[i] = h ? atomicAdd(&bcur[i], h) : 0;   // one reservation per (block,bucket)
        hist[i] = 0;                                   // reuse as local rank cursor
    }
    __syncthreads();
    #pragma unroll
    for (int r = 0; r < CH / 256; ++r) {
        const int e = e0 + r * 256 + tid;
        if (e < E) {
            const int d = ei[E + e];                   // L2-hot (2nd read of chunk)
            const int src = ei[e];                     // sequential stream
            const float w = ea[e];                     // sequential stream
            const float2 xv = ((const float2*)x)[src]; // gather into 800KB (L2-fit)
            const int b = d >> BN_SHIFT;
            const int pos = base_s[b] + atomicAdd(&hist[b], 1);
            A[pos] = make_float4(xv.x, xv.y, w, __int_as_float(d));
        }
    }
}

// ---------- pass 4: bucket-resident MFMA edge MLP + LDS aggregation + mean ----------
// One 256-thread WG (4 waves) per 128-node bucket.
//  - Round-8 proven core: per-lane own-edge h1 (wave-uniform W1 -> SGPR), hi/lo bf16
//    split, 8KB/wave k-split XOR-swizzled staging, 48 MFMAs into acc[4][4].
//  - Epilogue: 16 shfl(dst) + 64 LDS atomicAdd per lane into aggl[128][65]
//    (stride 65 scatters banks; col 64 = edge count), then mean flush to agg.
__global__ __launch_bounds__(256, 2) void bucket_kernel(
    const float4* __restrict__ A, const int* __restrict__ boff,
    const float* __restrict__ W1, const float* __restrict__ b1,
    const unsigned short* __restrict__ Bhi, const unsigned short* __restrict__ Blo,
    const float* __restrict__ b2,
    float* __restrict__ agg, int N)
{
    __shared__ float aggl[BROWS * 65];                       // 33,280 B
    __shared__ __align__(16) unsigned int stg[4 * 2048];     // 32 KB: 8KB per wave
    const int b = blockIdx.x;
    const int lo = b << BN_SHIFT;
    const int span = min(BROWS, N - lo);
    const int start = boff[b], end = boff[b + 1];
    const int tid = threadIdx.x;

    for (int i = tid; i < BROWS * 65; i += 256) aggl[i] = 0.f;
    __syncthreads();

    const int wv = tid >> 6, lane = tid & 63;
    const int am = lane & 15, aq = lane >> 4;
    const int rsw = (lane & 7) << 4;
    unsigned int* stw = stg + wv * 2048;
    char* stb = (char*)stw;

    float bias[4];
    #pragma unroll
    for (int fb = 0; fb < 4; ++fb) bias[fb] = b2[fb * 16 + am];

    const int nIter = (end - start + 255) >> 8;
    for (int it = 0; it < nIter; ++it) {
        const int i = start + (it << 8) + (wv << 6) + lane;
        float gx0 = 0.f, gx1 = 0.f, gea = 0.f;
        int dstl = -1;
        if (i < end) {
            const float4 g = A[i];                           // streaming
            gx0 = g.x; gx1 = g.y; gea = g.z;
            dstl = __float_as_int(g.w) - lo;
        }
        if (dstl >= 0) atomicAdd(&aggl[dstl * 65 + 64], 1.0f);   // count

        f32x4 acc[4][4];
        #pragma unroll
        for (int a = 0; a < 4; ++a)
            #pragma unroll
            for (int c = 0; c < 4; ++c) acc[a][c] = (f32x4){0.f, 0.f, 0.f, 0.f};

        #pragma unroll
        for (int kb = 0; kb < 2; ++kb) {
            // phase 1: feats kb*32..+31; per-edge 128B row = [hi 64B | lo 64B], XOR-swizzled
            #pragma unroll
            for (int jc = 0; jc < 4; ++jc) {
                unsigned int hp[4], lp[4];
                #pragma unroll
                for (int jp = 0; jp < 4; ++jp) {
                    const int j0 = kb * 32 + jc * 8 + jp * 2;   // compile-time -> W1 via s_load
                    float v0 = fmaf(gx0, W1[j0],     fmaf(gx1, W1[64 + j0],     fmaf(gea, W1[128 + j0],     b1[j0])));
                    float v1 = fmaf(gx0, W1[j0 + 1], fmaf(gx1, W1[64 + j0 + 1], fmaf(gea, W1[128 + j0 + 1], b1[j0 + 1])));
                    v0 = fmaxf(v0, 0.f); v1 = fmaxf(v1, 0.f);
                    const unsigned int u0 = __float_as_uint(v0), u1 = __float_as_uint(v1);
                    hp[jp] = (u0 >> 16) | (u1 & 0xffff0000u);
                    const float r0 = v0 - __uint_as_float(u0 & 0xffff0000u);
                    const float r1 = v1 - __uint_as_float(u1 & 0xffff0000u);
                    lp[jp] = (__float_as_uint(r0) >> 16) | (__float_as_uint(r1) & 0xffff0000u);
                }
                const int boffb = (lane * 128 + jc * 16) ^ rsw;
                *(uint4*)(stb + boffb)        = make_uint4(hp[0], hp[1], hp[2], hp[3]);
                *(uint4*)(stb + (boffb ^ 64)) = make_uint4(lp[0], lp[1], lp[2], lp[3]);
            }

            s8v ah[4], al[4], bh[4], bl[4];
            #pragma unroll
            for (int eb = 0; eb < 4; ++eb) {
                const int ar = eb * 16 + am;
                const int ao = (ar * 128 + aq * 16) ^ ((ar & 7) << 4);
                ah[eb] = *(const s8v*)(stb + ao);
                al[eb] = *(const s8v*)(stb + (ao ^ 64));
            }
            #pragma unroll
            for (int fb = 0; fb < 4; ++fb) {
                const int bo = (fb * 16 + am) * 64 + kb * 32 + aq * 8;
                bh[fb] = *(const s8v*)(Bhi + bo);
                bl[fb] = *(const s8v*)(Blo + bo);
            }
            asm volatile("" ::: "memory");   // keep next-kb stores after this kb's LDS reads

            #pragma unroll
            for (int eb = 0; eb < 4; ++eb)
                #pragma unroll
                for (int fb = 0; fb < 4; ++fb) {
                    acc[eb][fb] = __builtin_amdgcn_mfma_f32_16x16x32_bf16(ah[eb], bh[fb], acc[eb][fb], 0, 0, 0);
                    acc[eb][fb] = __builtin_amdgcn_mfma_f32_16x16x32_bf16(ah[eb], bl[fb], acc[eb][fb], 0, 0, 0);
                    acc[eb][fb] = __builtin_amdgcn_mfma_f32_16x16x32_bf16(al[eb], bh[fb], acc[eb][fb], 0, 0, 0);
                }
        }
        asm volatile("" ::: "memory");   // frag reads done before next iteration's stores

        // epilogue: bias+relu, LDS atomic accumulate into this bucket's rows
        #pragma unroll
        for (int eb = 0; eb < 4; ++eb) {
            #pragma unroll
            for (int r = 0; r < 4; ++r) {
                const int drow = __shfl(dstl, eb * 16 + aq * 4 + r);
                if (drow >= 0) {
                    #pragma unroll
                    for (int fb = 0; fb < 4; ++fb) {
                        const float v = fmaxf(acc[eb][fb][r] + bias[fb], 0.f);
                        atomicAdd(&aggl[drow * 65 + fb * 16 + am], v);
                    }
                }
            }
        }
    }
    __syncthreads();

    // flush means: 2 threads per row, 32 feats each
    const int row = tid >> 1;
    const int f0 = (tid & 1) << 5;
    if (row < span) {
        const float c = aggl[row * 65 + 64];
        const float inv = 1.f / fmaxf(c, 1.f);
        float4* op = (float4*)(agg + (size_t)(lo + row) * HID + f0);
        #pragma unroll
        for (int q = 0; q < 8; ++q) {
            float4 vv;
            vv.x = aggl[row * 65 + f0 + q * 4 + 0] * inv;
            vv.y = aggl[row * 65 + f0 + q * 4 + 1] * inv;
            vv.z = aggl[row * 65 + f0 + q * 4 + 2] * inv;
            vv.w = aggl[row * 65 + f0 + q * 4 + 3] * inv;
            op[q] = vv;
        }
    }
}

// ---------- pass 5: node MLP (W3 pre-folded into C; agg already holds means) ----------
__global__ __launch_bounds__(256) void node_kernel(
    const float* __restrict__ x, const float* __restrict__ u,
    const int* __restrict__ batch,
    const float* __restrict__ W4, const float* __restrict__ W5,
    const float* __restrict__ b5,
    const float* __restrict__ C, const float* __restrict__ b4p,
    const float* __restrict__ agg,
    float* __restrict__ out, int N)
{
    const int n = blockIdx.x * 256 + threadIdx.x;
    if (n >= N) return;

    const float4* ar = (const float4*)(agg + (size_t)n * HID);

    float acc[67];
    #pragma unroll
    for (int j = 0; j < 67; ++j) acc[j] = b4p[j];

    #pragma unroll 4
    for (int q = 0; q < 16; ++q) {
        const float4 m4 = ar[q];
        const float mk[4] = {m4.x, m4.y, m4.z, m4.w};
        #pragma unroll
        for (int r = 0; r < 4; ++r) {
            const float* cr = C + (q * 4 + r) * 67;
            #pragma unroll
            for (int j = 0; j < 67; ++j) acc[j] = fmaf(mk[r], cr[j], acc[j]);
        }
    }

    const float2 xv = ((const float2*)x)[n];
    const float ub = u[batch[n]];
    #pragma unroll
    for (int j = 0; j < 67; ++j) acc[j] = fmaf(xv.x, W4[j], acc[j]);
    #pragma unroll
    for (int j = 0; j < 67; ++j) acc[j] = fmaf(xv.y, W4[67 + j], acc[j]);
    #pragma unroll
    for (int j = 0; j < 67; ++j) acc[j] = fmaf(ub, W4[66 * 67 + j], acc[j]);

    float o0 = b5[0], o1 = b5[1];
    #pragma unroll
    for (int j = 0; j < 67; ++j) {
        const float z = fmaxf(acc[j], 0.f);
        o0 = fmaf(z, W5[2 * j], o0);
        o1 = fmaf(z, W5[2 * j + 1], o1);
    }
    out[2 * n] = o0;
    out[2 * n + 1] = o1;
}

extern "C" void kernel_launch(void* const* d_in, const int* in_sizes, int n_in,
                              void* d_out, int out_size, void* d_ws, size_t ws_size,
                              hipStream_t stream) {
    const float* x     = (const float*)d_in[0];
    const int*   ei    = (const int*)  d_in[1];
    const float* ea    = (const float*)d_in[2];
    const float* u     = (const float*)d_in[3];
    const int*   batch = (const int*)  d_in[4];
    const float* W1 = (const float*)d_in[5];  const float* b1 = (const float*)d_in[6];
    const float* W2 = (const float*)d_in[7];  const float* b2 = (const float*)d_in[8];
    const float* W3 = (const float*)d_in[9];  const float* b3 = (const float*)d_in[10];
    const float* W4 = (const float*)d_in[11]; const float* b4 = (const float*)d_in[12];
    const float* W5 = (const float*)d_in[13]; const float* b5 = (const float*)d_in[14];

    const int N = in_sizes[0] / 2;   // 100000
    const int E = in_sizes[2];       // 1600000
    const int NB = (N + BROWS - 1) >> BN_SHIFT;   // 782 buckets

    // workspace layout (~51.3 MB)
    char* w = (char*)d_ws;
    size_t o = 0;
    int* bhist = (int*)(w + o); o += NBMAX * 4;
    int* boff  = (int*)(w + o); o += (NBMAX + 1) * 4;
    int* bcur  = (int*)(w + o); o += NBMAX * 4;
    o = (o + 15) & ~(size_t)15;
    unsigned short* Bhi = (unsigned short*)(w + o); o += 64 * 64 * 2;
    unsigned short* Blo = (unsigned short*)(w + o); o += 64 * 64 * 2;
    float* Cmat = (float*)(w + o); o += 64 * 67 * 4;
    float* b4p  = (float*)(w + o); o += 68 * 4;
    o = (o + 15) & ~(size_t)15;
    float4* Abuf = (float4*)(w + o); o += (size_t)E * 16;      // bucket-sorted payload
    float*  agg  = (float*)(w + o);  o += (size_t)N * HID * 4; // per-node means

    const int nCH = (E + CH - 1) / CH;   // 196

    hipMemsetAsync(bhist, 0, NBMAX * 4, stream);
    pack_w2_kernel<<<64, 64, 0, stream>>>(W2, Bhi, Blo);
    pack_w34_kernel<<<65, 128, 0, stream>>>(W3, b3, W4, b4, Cmat, b4p);
    bhist_kernel<<<nCH, 256, 0, stream>>>(ei, bhist, E, NB);
    bscan_kernel<<<1, 1024, 0, stream>>>(bhist, boff, bcur, NB);
    binA_kernel<<<nCH, 256, 0, stream>>>(ei, x, ea, bcur, Abuf, E, NB);
    bucket_kernel<<<NB, 256, 0, stream>>>(Abuf, boff, W1, b1, Bhi, Blo, b2, agg, N);
    node_kernel<<<(N + 255) / 256, 256, 0, stream>>>(x, u, batch, W4, W5, b5, Cmat, b4p,
                                                     agg, (float*)d_out, N);
}

// Round 11
// 201.715 us; speedup vs baseline: 4.2817x; 4.0157x over previous
//
#include <hip/hip_runtime.h>

// Node model GNN — bucket-resident fused aggregation, take 3 (native int LDS atomics):
//   edge MLP: h = relu(relu([x[src],ea]@W1+b1)@W2+b2)   (W3 commuted past the mean)
//   node: out = relu(mean@(W3@W4mid) + x-terms + (b4+b3@W4mid))@W5+b5   (W3 folded)
// Pipeline: bhist -> bscan -> binA (bucket-sort payload, merged writes)
//           -> bucket_kernel (round-8 MFMA core + FIXED-POINT ds_add_u32 aggregation)
//           -> node MLP.
// Round-9/10 lesson: fp32 atomicAdd on __shared__ lowers to a CAS loop (no native
// LDS fp atomic without unsafe-fp-atomics) -> ~120cyc/retry under contention was the
// 700us stall. Integer ds_add_u32 is always native; accumulate round(v*2^18).
constexpr int HID = 64;
constexpr int BN_SHIFT = 6;            // 64 nodes per bucket
constexpr int BROWS = 1 << BN_SHIFT;
constexpr int CH = 8192;               // edges per histogram/binA workgroup
constexpr int NBMAX = 2048;
constexpr float FPSCALE = 262144.f;    // 2^18
constexpr float INV_FPSCALE = 1.f / 262144.f;

typedef __attribute__((ext_vector_type(8))) short s8v;    // 8 bf16 MFMA A/B frag
typedef __attribute__((ext_vector_type(4))) float f32x4;  // MFMA C/D frag

// ---------- pass 0a: split W2 into transposed bf16 hi/lo tables ----------
__global__ __launch_bounds__(64) void pack_w2_kernel(
    const float* __restrict__ W2, unsigned short* __restrict__ Bhi,
    unsigned short* __restrict__ Blo)
{
    const int f = blockIdx.x;    // 64 blocks
    const int k = threadIdx.x;   // 64 threads
    const float w = W2[k * 64 + f];
    const unsigned int u = __float_as_uint(w);
    const float hf = __uint_as_float(u & 0xffff0000u);
    const float r = w - hf;
    Bhi[f * 64 + k] = (unsigned short)(u >> 16);
    Blo[f * 64 + k] = (unsigned short)(__float_as_uint(r) >> 16);
}

// ---------- pass 0b: fold W3 into W4's middle rows ----------
__global__ __launch_bounds__(128) void pack_w34_kernel(
    const float* __restrict__ W3, const float* __restrict__ b3,
    const float* __restrict__ W4, const float* __restrict__ b4,
    float* __restrict__ C, float* __restrict__ b4p)
{
    const int t = blockIdx.x;    // 0..64; t==64 computes the folded bias
    const int j = threadIdx.x;
    if (j >= 67) return;
    if (t < 64) {
        float s = 0.f;
        for (int k = 0; k < 64; ++k) s = fmaf(W3[t * 64 + k], W4[(2 + k) * 67 + j], s);
        C[t * 67 + j] = s;
    } else {
        float s = b4[j];
        for (int k = 0; k < 64; ++k) s = fmaf(b3[k], W4[(2 + k) * 67 + j], s);
        b4p[j] = s;
    }
}

// ---------- pass 1: bucket histogram (LDS-aggregated, int atomics) ----------
__global__ __launch_bounds__(256) void bhist_kernel(
    const int* __restrict__ ei, int* __restrict__ bhist, int E, int NB)
{
    __shared__ int h[NBMAX];
    const int tid = threadIdx.x;
    for (int i = tid; i < NB; i += 256) h[i] = 0;
    __syncthreads();
    const int e0 = blockIdx.x * CH;
    #pragma unroll
    for (int r = 0; r < CH / 256; ++r) {
        const int e = e0 + r * 256 + tid;
        if (e < E) atomicAdd(&h[ei[E + e] >> BN_SHIFT], 1);
    }
    __syncthreads();
    for (int i = tid; i < NB; i += 256)
        if (h[i]) atomicAdd(&bhist[i], h[i]);
}

// ---------- pass 2: bucket offsets scan (single block, chunked with carry) ----------
__global__ __launch_bounds__(1024) void bscan_kernel(
    const int* __restrict__ bhist, int* __restrict__ boff,
    int* __restrict__ bcur, int NB)
{
    __shared__ int sm[1024];
    __shared__ int carry;
    const int t = threadIdx.x;
    if (t == 0) carry = 0;
    __syncthreads();
    for (int base = 0; base < NB; base += 1024) {
        const int i = base + t;
        const int v = (i < NB) ? bhist[i] : 0;
        sm[t] = v;
        __syncthreads();
        for (int off = 1; off < 1024; off <<= 1) {
            int x = (t >= off) ? sm[t - off] : 0;
            __syncthreads();
            sm[t] += x;
            __syncthreads();
        }
        const int incl = sm[t];
        const int c = carry;
        __syncthreads();
        if (i < NB) { boff[i] = c + incl - v; bcur[i] = c + incl - v; }
        if (t == 1023) carry = c + incl;
        __syncthreads();
    }
    if (t == 0) boff[NB] = carry;
}

// ---------- pass 3: bucket-sort full payload (merged writes) ----------
__global__ __launch_bounds__(256) void binA_kernel(
    const int* __restrict__ ei, const float* __restrict__ x,
    const float* __restrict__ ea, int* __restrict__ bcur,
    float4* __restrict__ A, int E, int NB)
{
    __shared__ int hist[NBMAX];
    __shared__ int base_s[NBMAX];
    const int tid = threadIdx.x;
    const int e0 = blockIdx.x * CH;

    for (int i = tid; i < NB; i += 256) hist[i] = 0;
    __syncthreads();
    #pragma unroll
    for (int r = 0; r < CH / 256; ++r) {
        const int e = e0 + r * 256 + tid;
        if (e < E) atomicAdd(&hist[ei[E + e] >> BN_SHIFT], 1);
    }
    __syncthreads();
    for (int i = tid; i < NB; i += 256) {
        const int h = hist[i];
        base_s[i] = h ? atomicAdd(&bcur[i], h) : 0;   // one reservation per (block,bucket)
        hist[i] = 0;                                   // reuse as local rank cursor
    }
    __syncthreads();
    #pragma unroll
    for (int r = 0; r < CH / 256; ++r) {
        const int e = e0 + r * 256 + tid;
        if (e < E) {
            const int d = ei[E + e];                   // L2-hot (2nd read of chunk)
            const int src = ei[e];                     // sequential stream
            const float w = ea[e];                     // sequential stream
            const float2 xv = ((const float2*)x)[src]; // gather into 800KB (L2-fit)
            const int b = d >> BN_SHIFT;
            const int pos = base_s[b] + atomicAdd(&hist[b], 1);
            A[pos] = make_float4(xv.x, xv.y, w, __int_as_float(d));
        }
    }
}

// ---------- pass 4: bucket-resident MFMA edge MLP + fixed-point LDS aggregation ----------
// One 256-thread WG (4 waves) per 64-node bucket. LDS = aggl 16.6KB + staging 32KB
// = 49.4KB -> 3 WG/CU. Round-8 proven core (per-lane own-edge h1, wave-uniform W1,
// hi/lo bf16 split, 8KB/wave XOR-swizzled k-split staging, 48 MFMAs).
// Epilogue: 16 shfl(dst) + 64 native ds_add_u32 per lane of round(v*2^18).
__global__ __launch_bounds__(256, 2) void bucket_kernel(
    const float4* __restrict__ A, const int* __restrict__ boff,
    const float* __restrict__ W1, const float* __restrict__ b1,
    const unsigned short* __restrict__ Bhi, const unsigned short* __restrict__ Blo,
    const float* __restrict__ b2,
    float* __restrict__ agg, int N)
{
    __shared__ int aggl[BROWS * 65];                         // 16,640 B (col 64 = count)
    __shared__ __align__(16) unsigned int stg[4 * 2048];     // 32 KB: 8KB per wave
    const int b = blockIdx.x;
    const int lo = b << BN_SHIFT;
    const int span = min(BROWS, N - lo);
    const int start = boff[b], end = boff[b + 1];
    const int tid = threadIdx.x;

    for (int i = tid; i < BROWS * 65; i += 256) aggl[i] = 0;
    __syncthreads();

    const int wv = tid >> 6, lane = tid & 63;
    const int am = lane & 15, aq = lane >> 4;
    const int rsw = (lane & 7) << 4;
    unsigned int* stw = stg + wv * 2048;
    char* stb = (char*)stw;

    float bias[4];
    #pragma unroll
    for (int fb = 0; fb < 4; ++fb) bias[fb] = b2[fb * 16 + am];

    const int nIter = (end - start + 255) >> 8;
    for (int it = 0; it < nIter; ++it) {
        const int i = start + (it << 8) + (wv << 6) + lane;
        float gx0 = 0.f, gx1 = 0.f, gea = 0.f;
        int dstl = -1;
        if (i < end) {
            const float4 g = A[i];                           // streaming
            gx0 = g.x; gx1 = g.y; gea = g.z;
            dstl = __float_as_int(g.w) - lo;
        }
        if (dstl >= 0) atomicAdd(&aggl[dstl * 65 + 64], 1);  // native ds_add_u32

        f32x4 acc[4][4];
        #pragma unroll
        for (int a = 0; a < 4; ++a)
            #pragma unroll
            for (int c = 0; c < 4; ++c) acc[a][c] = (f32x4){0.f, 0.f, 0.f, 0.f};

        #pragma unroll
        for (int kb = 0; kb < 2; ++kb) {
            // phase 1: feats kb*32..+31; per-edge 128B row = [hi 64B | lo 64B], XOR-swizzled
            #pragma unroll
            for (int jc = 0; jc < 4; ++jc) {
                unsigned int hp[4], lp[4];
                #pragma unroll
                for (int jp = 0; jp < 4; ++jp) {
                    const int j0 = kb * 32 + jc * 8 + jp * 2;   // compile-time -> W1 via s_load
                    float v0 = fmaf(gx0, W1[j0],     fmaf(gx1, W1[64 + j0],     fmaf(gea, W1[128 + j0],     b1[j0])));
                    float v1 = fmaf(gx0, W1[j0 + 1], fmaf(gx1, W1[64 + j0 + 1], fmaf(gea, W1[128 + j0 + 1], b1[j0 + 1])));
                    v0 = fmaxf(v0, 0.f); v1 = fmaxf(v1, 0.f);
                    const unsigned int u0 = __float_as_uint(v0), u1 = __float_as_uint(v1);
                    hp[jp] = (u0 >> 16) | (u1 & 0xffff0000u);
                    const float r0 = v0 - __uint_as_float(u0 & 0xffff0000u);
                    const float r1 = v1 - __uint_as_float(u1 & 0xffff0000u);
                    lp[jp] = (__float_as_uint(r0) >> 16) | (__float_as_uint(r1) & 0xffff0000u);
                }
                const int boffb = (lane * 128 + jc * 16) ^ rsw;
                *(uint4*)(stb + boffb)        = make_uint4(hp[0], hp[1], hp[2], hp[3]);
                *(uint4*)(stb + (boffb ^ 64)) = make_uint4(lp[0], lp[1], lp[2], lp[3]);
            }

            s8v ah[4], al[4], bh[4], bl[4];
            #pragma unroll
            for (int eb = 0; eb < 4; ++eb) {
                const int ar = eb * 16 + am;
                const int ao = (ar * 128 + aq * 16) ^ ((ar & 7) << 4);
                ah[eb] = *(const s8v*)(stb + ao);
                al[eb] = *(const s8v*)(stb + (ao ^ 64));
            }
            #pragma unroll
            for (int fb = 0; fb < 4; ++fb) {
                const int bo = (fb * 16 + am) * 64 + kb * 32 + aq * 8;
                bh[fb] = *(const s8v*)(Bhi + bo);
                bl[fb] = *(const s8v*)(Blo + bo);
            }
            asm volatile("" ::: "memory");   // keep next-kb stores after this kb's LDS reads

            #pragma unroll
            for (int eb = 0; eb < 4; ++eb)
                #pragma unroll
                for (int fb = 0; fb < 4; ++fb) {
                    acc[eb][fb] = __builtin_amdgcn_mfma_f32_16x16x32_bf16(ah[eb], bh[fb], acc[eb][fb], 0, 0, 0);
                    acc[eb][fb] = __builtin_amdgcn_mfma_f32_16x16x32_bf16(ah[eb], bl[fb], acc[eb][fb], 0, 0, 0);
                    acc[eb][fb] = __builtin_amdgcn_mfma_f32_16x16x32_bf16(al[eb], bh[fb], acc[eb][fb], 0, 0, 0);
                }
        }
        asm volatile("" ::: "memory");   // frag reads done before next iteration's stores

        // epilogue: bias+relu, fixed-point native LDS atomics into bucket rows
        #pragma unroll
        for (int eb = 0; eb < 4; ++eb) {
            #pragma unroll
            for (int r = 0; r < 4; ++r) {
                const int drow = __shfl(dstl, eb * 16 + aq * 4 + r);
                if (drow >= 0) {
                    #pragma unroll
                    for (int fb = 0; fb < 4; ++fb) {
                        const float v = fmaxf(acc[eb][fb][r] + bias[fb], 0.f);
                        atomicAdd(&aggl[drow * 65 + fb * 16 + am], __float2int_rn(v * FPSCALE));
                    }
                }
            }
        }
    }
    __syncthreads();

    // flush means: 4 threads per row, 16 feats each
    const int row = tid >> 2;
    const int f0 = (tid & 3) << 4;
    if (row < span) {
        const float c = (float)aggl[row * 65 + 64];
        const float inv = INV_FPSCALE / fmaxf(c, 1.f);
        float4* op = (float4*)(agg + (size_t)(lo + row) * HID + f0);
        #pragma unroll
        for (int q = 0; q < 4; ++q) {
            float4 vv;
            vv.x = (float)aggl[row * 65 + f0 + q * 4 + 0] * inv;
            vv.y = (float)aggl[row * 65 + f0 + q * 4 + 1] * inv;
            vv.z = (float)aggl[row * 65 + f0 + q * 4 + 2] * inv;
            vv.w = (float)aggl[row * 65 + f0 + q * 4 + 3] * inv;
            op[q] = vv;
        }
    }
}

// ---------- pass 5: node MLP (W3 pre-folded into C; agg already holds means) ----------
__global__ __launch_bounds__(256) void node_kernel(
    const float* __restrict__ x, const float* __restrict__ u,
    const int* __restrict__ batch,
    const float* __restrict__ W4, const float* __restrict__ W5,
    const float* __restrict__ b5,
    const float* __restrict__ C, const float* __restrict__ b4p,
    const float* __restrict__ agg,
    float* __restrict__ out, int N)
{
    const int n = blockIdx.x * 256 + threadIdx.x;
    if (n >= N) return;

    const float4* ar = (const float4*)(agg + (size_t)n * HID);

    float acc[67];
    #pragma unroll
    for (int j = 0; j < 67; ++j) acc[j] = b4p[j];

    #pragma unroll 4
    for (int q = 0; q < 16; ++q) {
        const float4 m4 = ar[q];
        const float mk[4] = {m4.x, m4.y, m4.z, m4.w};
        #pragma unroll
        for (int r = 0; r < 4; ++r) {
            const float* cr = C + (q * 4 + r) * 67;
            #pragma unroll
            for (int j = 0; j < 67; ++j) acc[j] = fmaf(mk[r], cr[j], acc[j]);
        }
    }

    const float2 xv = ((const float2*)x)[n];
    const float ub = u[batch[n]];
    #pragma unroll
    for (int j = 0; j < 67; ++j) acc[j] = fmaf(xv.x, W4[j], acc[j]);
    #pragma unroll
    for (int j = 0; j < 67; ++j) acc[j] = fmaf(xv.y, W4[67 + j], acc[j]);
    #pragma unroll
    for (int j = 0; j < 67; ++j) acc[j] = fmaf(ub, W4[66 * 67 + j], acc[j]);

    float o0 = b5[0], o1 = b5[1];
    #pragma unroll
    for (int j = 0; j < 67; ++j) {
        const float z = fmaxf(acc[j], 0.f);
        o0 = fmaf(z, W5[2 * j], o0);
        o1 = fmaf(z, W5[2 * j + 1], o1);
    }
    out[2 * n] = o0;
    out[2 * n + 1] = o1;
}

extern "C" void kernel_launch(void* const* d_in, const int* in_sizes, int n_in,
                              void* d_out, int out_size, void* d_ws, size_t ws_size,
                              hipStream_t stream) {
    const float* x     = (const float*)d_in[0];
    const int*   ei    = (const int*)  d_in[1];
    const float* ea    = (const float*)d_in[2];
    const float* u     = (const float*)d_in[3];
    const int*   batch = (const int*)  d_in[4];
    const float* W1 = (const float*)d_in[5];  const float* b1 = (const float*)d_in[6];
    const float* W2 = (const float*)d_in[7];  const float* b2 = (const float*)d_in[8];
    const float* W3 = (const float*)d_in[9];  const float* b3 = (const float*)d_in[10];
    const float* W4 = (const float*)d_in[11]; const float* b4 = (const float*)d_in[12];
    const float* W5 = (const float*)d_in[13]; const float* b5 = (const float*)d_in[14];

    const int N = in_sizes[0] / 2;   // 100000
    const int E = in_sizes[2];       // 1600000
    const int NB = (N + BROWS - 1) >> BN_SHIFT;   // 1563 buckets

    // workspace layout (~51.3 MB)
    char* w = (char*)d_ws;
    size_t o = 0;
    int* bhist = (int*)(w + o); o += NBMAX * 4;
    int* boff  = (int*)(w + o); o += (NBMAX + 1) * 4;
    int* bcur  = (int*)(w + o); o += NBMAX * 4;
    o = (o + 15) & ~(size_t)15;
    unsigned short* Bhi = (unsigned short*)(w + o); o += 64 * 64 * 2;
    unsigned short* Blo = (unsigned short*)(w + o); o += 64 * 64 * 2;
    float* Cmat = (float*)(w + o); o += 64 * 67 * 4;
    float* b4p  = (float*)(w + o); o += 68 * 4;
    o = (o + 15) & ~(size_t)15;
    float4* Abuf = (float4*)(w + o); o += (size_t)E * 16;      // bucket-sorted payload
    float*  agg  = (float*)(w + o);  o += (size_t)N * HID * 4; // per-node means

    const int nCH = (E + CH - 1) / CH;   // 196

    hipMemsetAsync(bhist, 0, NBMAX * 4, stream);
    pack_w2_kernel<<<64, 64, 0, stream>>>(W2, Bhi, Blo);
    pack_w34_kernel<<<65, 128, 0, stream>>>(W3, b3, W4, b4, Cmat, b4p);
    bhist_kernel<<<nCH, 256, 0, stream>>>(ei, bhist, E, NB);
    bscan_kernel<<<1, 1024, 0, stream>>>(bhist, boff, bcur, NB);
    binA_kernel<<<nCH, 256, 0, stream>>>(ei, x, ea, bcur, Abuf, E, NB);
    bucket_kernel<<<NB, 256, 0, stream>>>(Abuf, boff, W1, b1, Bhi, Blo, b2, agg, N);
    node_kernel<<<(N + 255) / 256, 256, 0, stream>>>(x, u, batch, W4, W5, b5, Cmat, b4p,
                                                     agg, (float*)d_out, N);
}